// Round 1
// baseline (403.275 us; speedup 1.0000x reference)
//
#include <hip/hip_runtime.h>
#include <math.h>

#define B_ 4
#define T_ 4096
#define D_ 2048
#define E_ 8
#define C_ 1024
#define H_ 256

typedef unsigned short u16;
typedef __attribute__((ext_vector_type(8))) short short8;
typedef __attribute__((ext_vector_type(4))) float f32x4;

__device__ __forceinline__ u16 f2bf(float f) {
    union { float f; unsigned u; } v; v.f = f;
    unsigned r = (v.u + 0x7FFFu + ((v.u >> 16) & 1u)) >> 16;
    return (u16)r;
}

// ---------------- f32 -> bf16 weight conversion ----------------
__global__ __launch_bounds__(256) void conv_f32_bf16(
    const float* __restrict__ src, u16* __restrict__ dst, int n)
{
    int i = (blockIdx.x * 256 + threadIdx.x) * 4;
    if (i >= n) return;
    f32x4 v = *reinterpret_cast<const f32x4*>(src + i);
    u16 o[4];
    o[0] = f2bf(v[0]); o[1] = f2bf(v[1]); o[2] = f2bf(v[2]); o[3] = f2bf(v[3]);
    *reinterpret_cast<ulonglong1*>(dst + i) =
        *reinterpret_cast<const ulonglong1*>(o);
}

// ---------------- GEMM1: h = gelu(sel @ W1^T + b1) ----------------
// sel rows gathered from x via expert_indices; output Hbuf (B,E,C,H) bf16
__global__ __launch_bounds__(256) void gemm1_kernel(
    const float* __restrict__ x, const u16* __restrict__ W1bf,
    const float* __restrict__ b1, const int* __restrict__ idx,
    u16* __restrict__ Hbuf)
{
    const int bt = blockIdx.x;          // 0..15 = mt*2 + nt
    const int mt = bt >> 1, nt = bt & 1;
    const int be = blockIdx.y;          // 0..31
    const int b = be >> 3, e = be & 7;
    const int m0 = mt * 128, n0 = nt * 128;

    __shared__ __align__(16) u16 As[128][72];
    __shared__ __align__(16) u16 Bs[128][72];
    __shared__ int toks[128];

    const int tid = threadIdx.x;
    if (tid < 128) toks[tid] = idx[(b * E_ + e) * C_ + m0 + tid];
    __syncthreads();

    const int lane = tid & 63, wid = tid >> 6;
    const int wm = wid >> 1, wn = wid & 1;
    const int l15 = lane & 15, lk = lane >> 4;

    const int sr = tid >> 1;            // staging row 0..127
    const int sh = (tid & 1) * 32;      // staging col base (elements)

    const float* aSrc = x + (size_t)b * (T_ * (size_t)D_)
                          + (size_t)toks[sr] * D_ + sh;
    const u16* bSrc = W1bf + ((size_t)e * H_ + n0 + sr) * D_ + sh;

    f32x4 acc[4][4];
    #pragma unroll
    for (int i = 0; i < 4; ++i)
        #pragma unroll
        for (int j = 0; j < 4; ++j)
            acc[i][j] = (f32x4){0.f, 0.f, 0.f, 0.f};

    for (int k0 = 0; k0 < D_; k0 += 64) {
        __syncthreads();
        // stage A: 32 f32 -> 32 bf16 per thread
        #pragma unroll
        for (int j = 0; j < 4; ++j) {
            f32x4 v0 = *reinterpret_cast<const f32x4*>(aSrc + k0 + j * 8);
            f32x4 v1 = *reinterpret_cast<const f32x4*>(aSrc + k0 + j * 8 + 4);
            short8 p;
            p[0] = (short)f2bf(v0[0]); p[1] = (short)f2bf(v0[1]);
            p[2] = (short)f2bf(v0[2]); p[3] = (short)f2bf(v0[3]);
            p[4] = (short)f2bf(v1[0]); p[5] = (short)f2bf(v1[1]);
            p[6] = (short)f2bf(v1[2]); p[7] = (short)f2bf(v1[3]);
            *reinterpret_cast<short8*>(&As[sr][sh + j * 8]) = p;
        }
        // stage B: 32 bf16 per thread (already bf16)
        #pragma unroll
        for (int j = 0; j < 4; ++j) {
            *reinterpret_cast<short8*>(&Bs[sr][sh + j * 8]) =
                *reinterpret_cast<const short8*>(bSrc + k0 + j * 8);
        }
        __syncthreads();
        #pragma unroll
        for (int kk = 0; kk < 64; kk += 32) {
            short8 af[4], bfr[4];
            #pragma unroll
            for (int m = 0; m < 4; ++m)
                af[m] = *reinterpret_cast<const short8*>(
                    &As[wm * 64 + m * 16 + l15][kk + lk * 8]);
            #pragma unroll
            for (int n = 0; n < 4; ++n)
                bfr[n] = *reinterpret_cast<const short8*>(
                    &Bs[wn * 64 + n * 16 + l15][kk + lk * 8]);
            #pragma unroll
            for (int m = 0; m < 4; ++m)
                #pragma unroll
                for (int n = 0; n < 4; ++n)
                    acc[m][n] = __builtin_amdgcn_mfma_f32_16x16x32_bf16(
                        af[m], bfr[n], acc[m][n], 0, 0, 0);
        }
    }

    // epilogue: bias + exact gelu -> bf16 Hbuf
    const size_t hbase = (size_t)(b * E_ + e) * (C_ * (size_t)H_);
    #pragma unroll
    for (int n = 0; n < 4; ++n) {
        const int col = n0 + wn * 64 + n * 16 + l15;
        const float bias = b1[e * H_ + col];
        #pragma unroll
        for (int m = 0; m < 4; ++m) {
            const int rb = m0 + wm * 64 + m * 16 + lk * 4;
            #pragma unroll
            for (int r = 0; r < 4; ++r) {
                float h = acc[m][n][r] + bias;
                float g = 0.5f * h * (1.0f + erff(h * 0.70710678118f));
                Hbuf[hbase + (size_t)(rb + r) * H_ + col] = f2bf(g);
            }
        }
    }
}

// ---------------- GEMM2: y = (h @ W2^T + b2) * gate, scatter-add ----------------
__global__ __launch_bounds__(256) void gemm2_kernel(
    const u16* __restrict__ Hbuf, const u16* __restrict__ W2bf,
    const float* __restrict__ b2, const int* __restrict__ idx,
    const float* __restrict__ gate, float* __restrict__ out)
{
    const int mt = blockIdx.x >> 4, nt = blockIdx.x & 15;
    const int be = blockIdx.y;
    const int b = be >> 3, e = be & 7;
    const int m0 = mt * 128, n0 = nt * 128;

    __shared__ __align__(16) u16 As[128][72];
    __shared__ __align__(16) u16 Bs[128][72];

    const int tid = threadIdx.x;
    const int lane = tid & 63, wid = tid >> 6;
    const int wm = wid >> 1, wn = wid & 1;
    const int l15 = lane & 15, lk = lane >> 4;

    const int sr = tid >> 1;
    const int sh = (tid & 1) * 32;

    const u16* aSrc = Hbuf + ((size_t)(b * E_ + e) * C_ + m0 + sr) * H_ + sh;
    const u16* bSrc = W2bf + ((size_t)e * D_ + n0 + sr) * H_ + sh;

    f32x4 acc[4][4];
    #pragma unroll
    for (int i = 0; i < 4; ++i)
        #pragma unroll
        for (int j = 0; j < 4; ++j)
            acc[i][j] = (f32x4){0.f, 0.f, 0.f, 0.f};

    for (int k0 = 0; k0 < H_; k0 += 64) {
        __syncthreads();
        #pragma unroll
        for (int j = 0; j < 4; ++j) {
            *reinterpret_cast<short8*>(&As[sr][sh + j * 8]) =
                *reinterpret_cast<const short8*>(aSrc + k0 + j * 8);
            *reinterpret_cast<short8*>(&Bs[sr][sh + j * 8]) =
                *reinterpret_cast<const short8*>(bSrc + k0 + j * 8);
        }
        __syncthreads();
        #pragma unroll
        for (int kk = 0; kk < 64; kk += 32) {
            short8 af[4], bfr[4];
            #pragma unroll
            for (int m = 0; m < 4; ++m)
                af[m] = *reinterpret_cast<const short8*>(
                    &As[wm * 64 + m * 16 + l15][kk + lk * 8]);
            #pragma unroll
            for (int n = 0; n < 4; ++n)
                bfr[n] = *reinterpret_cast<const short8*>(
                    &Bs[wn * 64 + n * 16 + l15][kk + lk * 8]);
            #pragma unroll
            for (int m = 0; m < 4; ++m)
                #pragma unroll
                for (int n = 0; n < 4; ++n)
                    acc[m][n] = __builtin_amdgcn_mfma_f32_16x16x32_bf16(
                        af[m], bfr[n], acc[m][n], 0, 0, 0);
        }
    }

    // epilogue: (acc + b2) * gate, atomic scatter-add to out[b, tok, :]
    const int ibase = (b * E_ + e) * C_ + m0 + wm * 64;
    #pragma unroll
    for (int m = 0; m < 4; ++m) {
        #pragma unroll
        for (int r = 0; r < 4; ++r) {
            const int c = m * 16 + lk * 4 + r;
            const int tok = idx[ibase + c];
            const float g = gate[ibase + c];
            float* orow = out + ((size_t)b * T_ + tok) * D_ + n0 + wn * 64;
            #pragma unroll
            for (int n = 0; n < 4; ++n) {
                const int col = n * 16 + l15;
                const float v = (acc[m][n][r] + b2[n0 + wn * 64 + col]) * g;
                atomicAdd(orow + col, v);
            }
        }
    }
}

extern "C" void kernel_launch(void* const* d_in, const int* in_sizes, int n_in,
                              void* d_out, int out_size, void* d_ws, size_t ws_size,
                              hipStream_t stream) {
    const float* x    = (const float*)d_in[0];
    const float* W1   = (const float*)d_in[1];
    const float* b1   = (const float*)d_in[2];
    const float* W2   = (const float*)d_in[3];
    const float* b2   = (const float*)d_in[4];
    const int*   idx  = (const int*)d_in[5];
    const float* gate = (const float*)d_in[6];

    u16* W1bf = (u16*)d_ws;
    u16* W2bf = W1bf + (size_t)E_ * H_ * D_;
    u16* Hbuf = W2bf + (size_t)E_ * D_ * H_;
    float* out = (float*)d_out;

    hipMemsetAsync(d_out, 0, (size_t)B_ * T_ * D_ * sizeof(float), stream);

    const int nW = E_ * H_ * D_;  // 4,194,304
    conv_f32_bf16<<<nW / (256 * 4), 256, 0, stream>>>(W1, W1bf, nW);
    conv_f32_bf16<<<nW / (256 * 4), 256, 0, stream>>>(W2, W2bf, nW);

    gemm1_kernel<<<dim3(16, 32), 256, 0, stream>>>(x, W1bf, b1, idx, Hbuf);
    gemm2_kernel<<<dim3(128, 32), 256, 0, stream>>>(Hbuf, W2bf, b2, idx, gate, out);
}

// Round 2
// 291.132 us; speedup vs baseline: 1.3852x; 1.3852x over previous
//
#include <hip/hip_runtime.h>
#include <math.h>

#define B_ 4
#define T_ 4096
#define D_ 2048
#define E_ 8
#define C_ 1024
#define H_ 256
#define SLOTCAP 32

typedef unsigned short u16;
typedef __attribute__((ext_vector_type(8))) short short8;
typedef __attribute__((ext_vector_type(4))) float f32x4;

__device__ __forceinline__ u16 f2bf(float f) {
    union { float f; unsigned u; } v; v.f = f;
    unsigned r = (v.u + 0x7FFFu + ((v.u >> 16) & 1u)) >> 16;
    return (u16)r;
}
__device__ __forceinline__ float bf2f(u16 u) {
    union { unsigned u; float f; } v; v.u = ((unsigned)u) << 16;
    return v.f;
}

// ---------------- f32 -> bf16 conversion ----------------
__global__ __launch_bounds__(256) void conv_f32_bf16(
    const float* __restrict__ src, u16* __restrict__ dst, int n)
{
    int i = (blockIdx.x * 256 + threadIdx.x) * 4;
    if (i >= n) return;
    f32x4 v = *reinterpret_cast<const f32x4*>(src + i);
    u16 o[4];
    o[0] = f2bf(v[0]); o[1] = f2bf(v[1]); o[2] = f2bf(v[2]); o[3] = f2bf(v[3]);
    *reinterpret_cast<ulonglong1*>(dst + i) =
        *reinterpret_cast<const ulonglong1*>(o);
}

// ---------------- GEMM1 (bf16 x): h = gelu(sel @ W1^T + b1) ----------------
__global__ __launch_bounds__(256) void gemm1_bf(
    const u16* __restrict__ xbf, const u16* __restrict__ W1bf,
    const float* __restrict__ b1, const int* __restrict__ idx,
    u16* __restrict__ Hbuf)
{
    const int bt = blockIdx.x;          // 0..15 = mt*2 + nt
    const int mt = bt >> 1, nt = bt & 1;
    const int be = blockIdx.y;          // 0..31
    const int b = be >> 3, e = be & 7;
    const int m0 = mt * 128, n0 = nt * 128;

    __shared__ __align__(16) u16 As[128][72];
    __shared__ __align__(16) u16 Bs[128][72];
    __shared__ int toks[128];

    const int tid = threadIdx.x;
    if (tid < 128) toks[tid] = idx[(b * E_ + e) * C_ + m0 + tid];
    __syncthreads();

    const int lane = tid & 63, wid = tid >> 6;
    const int wm = wid >> 1, wn = wid & 1;
    const int l15 = lane & 15, lk = lane >> 4;

    const int sr = tid >> 1;
    const int sh = (tid & 1) * 32;

    const u16* aSrc = xbf + (size_t)b * (T_ * (size_t)D_)
                          + (size_t)toks[sr] * D_ + sh;
    const u16* bSrc = W1bf + ((size_t)e * H_ + n0 + sr) * D_ + sh;

    f32x4 acc[4][4];
    #pragma unroll
    for (int i = 0; i < 4; ++i)
        #pragma unroll
        for (int j = 0; j < 4; ++j)
            acc[i][j] = (f32x4){0.f, 0.f, 0.f, 0.f};

    for (int k0 = 0; k0 < D_; k0 += 64) {
        __syncthreads();
        #pragma unroll
        for (int j = 0; j < 4; ++j) {
            *reinterpret_cast<short8*>(&As[sr][sh + j * 8]) =
                *reinterpret_cast<const short8*>(aSrc + k0 + j * 8);
            *reinterpret_cast<short8*>(&Bs[sr][sh + j * 8]) =
                *reinterpret_cast<const short8*>(bSrc + k0 + j * 8);
        }
        __syncthreads();
        #pragma unroll
        for (int kk = 0; kk < 64; kk += 32) {
            short8 af[4], bfr[4];
            #pragma unroll
            for (int m = 0; m < 4; ++m)
                af[m] = *reinterpret_cast<const short8*>(
                    &As[wm * 64 + m * 16 + l15][kk + lk * 8]);
            #pragma unroll
            for (int n = 0; n < 4; ++n)
                bfr[n] = *reinterpret_cast<const short8*>(
                    &Bs[wn * 64 + n * 16 + l15][kk + lk * 8]);
            #pragma unroll
            for (int m = 0; m < 4; ++m)
                #pragma unroll
                for (int n = 0; n < 4; ++n)
                    acc[m][n] = __builtin_amdgcn_mfma_f32_16x16x32_bf16(
                        af[m], bfr[n], acc[m][n], 0, 0, 0);
        }
    }

    const size_t hbase = (size_t)(b * E_ + e) * (C_ * (size_t)H_);
    #pragma unroll
    for (int n = 0; n < 4; ++n) {
        const int col = n0 + wn * 64 + n * 16 + l15;
        const float bias = b1[e * H_ + col];
        #pragma unroll
        for (int m = 0; m < 4; ++m) {
            const int rb = m0 + wm * 64 + m * 16 + lk * 4;
            #pragma unroll
            for (int r = 0; r < 4; ++r) {
                float h = acc[m][n][r] + bias;
                float g = 0.5f * h * (1.0f + erff(h * 0.70710678118f));
                Hbuf[hbase + (size_t)(rb + r) * H_ + col] = f2bf(g);
            }
        }
    }
}

// ---------------- GEMM2: Ybuf = ((h @ W2^T) + b2) * gate  (bf16) ----------------
__global__ __launch_bounds__(256) void gemm2_y(
    const u16* __restrict__ Hbuf, const u16* __restrict__ W2bf,
    const float* __restrict__ b2, const float* __restrict__ gate,
    u16* __restrict__ Ybuf)
{
    const int mt = blockIdx.x >> 4, nt = blockIdx.x & 15;
    const int be = blockIdx.y;
    const int b = be >> 3, e = be & 7;
    const int m0 = mt * 128, n0 = nt * 128;

    __shared__ __align__(16) u16 As[128][72];
    __shared__ __align__(16) u16 Bs[128][72];
    __shared__ float gs[128];

    const int tid = threadIdx.x;
    if (tid < 128) gs[tid] = gate[(b * E_ + e) * C_ + m0 + tid];

    const int lane = tid & 63, wid = tid >> 6;
    const int wm = wid >> 1, wn = wid & 1;
    const int l15 = lane & 15, lk = lane >> 4;

    const int sr = tid >> 1;
    const int sh = (tid & 1) * 32;

    const u16* aSrc = Hbuf + ((size_t)(b * E_ + e) * C_ + m0 + sr) * H_ + sh;
    const u16* bSrc = W2bf + ((size_t)e * D_ + n0 + sr) * H_ + sh;

    f32x4 acc[4][4];
    #pragma unroll
    for (int i = 0; i < 4; ++i)
        #pragma unroll
        for (int j = 0; j < 4; ++j)
            acc[i][j] = (f32x4){0.f, 0.f, 0.f, 0.f};

    for (int k0 = 0; k0 < H_; k0 += 64) {
        __syncthreads();
        #pragma unroll
        for (int j = 0; j < 4; ++j) {
            *reinterpret_cast<short8*>(&As[sr][sh + j * 8]) =
                *reinterpret_cast<const short8*>(aSrc + k0 + j * 8);
            *reinterpret_cast<short8*>(&Bs[sr][sh + j * 8]) =
                *reinterpret_cast<const short8*>(bSrc + k0 + j * 8);
        }
        __syncthreads();
        #pragma unroll
        for (int kk = 0; kk < 64; kk += 32) {
            short8 af[4], bfr[4];
            #pragma unroll
            for (int m = 0; m < 4; ++m)
                af[m] = *reinterpret_cast<const short8*>(
                    &As[wm * 64 + m * 16 + l15][kk + lk * 8]);
            #pragma unroll
            for (int n = 0; n < 4; ++n)
                bfr[n] = *reinterpret_cast<const short8*>(
                    &Bs[wn * 64 + n * 16 + l15][kk + lk * 8]);
            #pragma unroll
            for (int m = 0; m < 4; ++m)
                #pragma unroll
                for (int n = 0; n < 4; ++n)
                    acc[m][n] = __builtin_amdgcn_mfma_f32_16x16x32_bf16(
                        af[m], bfr[n], acc[m][n], 0, 0, 0);
        }
    }

    // epilogue: (acc + b2) * gate -> bf16 Ybuf
    const size_t ybase = (size_t)(b * E_ + e) * C_ + m0;
    #pragma unroll
    for (int n = 0; n < 4; ++n) {
        const int col = n0 + wn * 64 + n * 16 + l15;
        const float bias = b2[col];
        #pragma unroll
        for (int m = 0; m < 4; ++m) {
            #pragma unroll
            for (int r = 0; r < 4; ++r) {
                const int cl = wm * 64 + m * 16 + lk * 4 + r;
                const float v = (acc[m][n][r] + bias) * gs[cl];
                Ybuf[(ybase + cl) * D_ + col] = f2bf(v);
            }
        }
    }
}

// ---------------- inverted index build ----------------
__global__ __launch_bounds__(256) void fill_kernel(
    const int* __restrict__ idx, int* __restrict__ cnt,
    int* __restrict__ slots)
{
    int i = blockIdx.x * 256 + threadIdx.x;
    if (i >= B_ * E_ * C_) return;
    int b = i / (E_ * C_);
    int slot = i % (E_ * C_);
    int t = idx[i];
    int p = atomicAdd(&cnt[b * T_ + t], 1);
    if (p < SLOTCAP) slots[(b * T_ + t) * SLOTCAP + p] = slot;
}

// ---------------- combine: out[b,t,:] = sum over slots of Ybuf ----------------
__global__ __launch_bounds__(256) void combine_kernel(
    const u16* __restrict__ Ybuf, const int* __restrict__ cnt,
    const int* __restrict__ slots, float* __restrict__ out)
{
    const int bt = blockIdx.x;               // b*T_ + t
    const int tid = threadIdx.x;
    __shared__ int sl[SLOTCAP];
    int n = cnt[bt];
    n = n > SLOTCAP ? SLOTCAP : n;
    if (tid < n) sl[tid] = slots[bt * SLOTCAP + tid];
    __syncthreads();
    const int b = bt >> 12;                  // T_ = 4096
    float a[8] = {0.f, 0.f, 0.f, 0.f, 0.f, 0.f, 0.f, 0.f};
    for (int s = 0; s < n; ++s) {
        const u16* yrow = Ybuf + ((size_t)b * (E_ * C_) + sl[s]) * D_ + tid * 8;
        short8 v = *reinterpret_cast<const short8*>(yrow);
        #pragma unroll
        for (int j = 0; j < 8; ++j) a[j] += bf2f((u16)v[j]);
    }
    float* orow = out + (size_t)bt * D_ + tid * 8;
    *reinterpret_cast<f32x4*>(orow)     = (f32x4){a[0], a[1], a[2], a[3]};
    *reinterpret_cast<f32x4*>(orow + 4) = (f32x4){a[4], a[5], a[6], a[7]};
}

// ============ fallback (round-1) kernels, used when ws is small ============
__global__ __launch_bounds__(256) void gemm1_f32(
    const float* __restrict__ x, const u16* __restrict__ W1bf,
    const float* __restrict__ b1, const int* __restrict__ idx,
    u16* __restrict__ Hbuf)
{
    const int bt = blockIdx.x;
    const int mt = bt >> 1, nt = bt & 1;
    const int be = blockIdx.y;
    const int b = be >> 3, e = be & 7;
    const int m0 = mt * 128, n0 = nt * 128;

    __shared__ __align__(16) u16 As[128][72];
    __shared__ __align__(16) u16 Bs[128][72];
    __shared__ int toks[128];

    const int tid = threadIdx.x;
    if (tid < 128) toks[tid] = idx[(b * E_ + e) * C_ + m0 + tid];
    __syncthreads();

    const int lane = tid & 63, wid = tid >> 6;
    const int wm = wid >> 1, wn = wid & 1;
    const int l15 = lane & 15, lk = lane >> 4;
    const int sr = tid >> 1;
    const int sh = (tid & 1) * 32;

    const float* aSrc = x + (size_t)b * (T_ * (size_t)D_)
                          + (size_t)toks[sr] * D_ + sh;
    const u16* bSrc = W1bf + ((size_t)e * H_ + n0 + sr) * D_ + sh;

    f32x4 acc[4][4];
    #pragma unroll
    for (int i = 0; i < 4; ++i)
        #pragma unroll
        for (int j = 0; j < 4; ++j)
            acc[i][j] = (f32x4){0.f, 0.f, 0.f, 0.f};

    for (int k0 = 0; k0 < D_; k0 += 64) {
        __syncthreads();
        #pragma unroll
        for (int j = 0; j < 4; ++j) {
            f32x4 v0 = *reinterpret_cast<const f32x4*>(aSrc + k0 + j * 8);
            f32x4 v1 = *reinterpret_cast<const f32x4*>(aSrc + k0 + j * 8 + 4);
            short8 p;
            p[0] = (short)f2bf(v0[0]); p[1] = (short)f2bf(v0[1]);
            p[2] = (short)f2bf(v0[2]); p[3] = (short)f2bf(v0[3]);
            p[4] = (short)f2bf(v1[0]); p[5] = (short)f2bf(v1[1]);
            p[6] = (short)f2bf(v1[2]); p[7] = (short)f2bf(v1[3]);
            *reinterpret_cast<short8*>(&As[sr][sh + j * 8]) = p;
            *reinterpret_cast<short8*>(&Bs[sr][sh + j * 8]) =
                *reinterpret_cast<const short8*>(bSrc + k0 + j * 8);
        }
        __syncthreads();
        #pragma unroll
        for (int kk = 0; kk < 64; kk += 32) {
            short8 af[4], bfr[4];
            #pragma unroll
            for (int m = 0; m < 4; ++m)
                af[m] = *reinterpret_cast<const short8*>(
                    &As[wm * 64 + m * 16 + l15][kk + lk * 8]);
            #pragma unroll
            for (int n = 0; n < 4; ++n)
                bfr[n] = *reinterpret_cast<const short8*>(
                    &Bs[wn * 64 + n * 16 + l15][kk + lk * 8]);
            #pragma unroll
            for (int m = 0; m < 4; ++m)
                #pragma unroll
                for (int n = 0; n < 4; ++n)
                    acc[m][n] = __builtin_amdgcn_mfma_f32_16x16x32_bf16(
                        af[m], bfr[n], acc[m][n], 0, 0, 0);
        }
    }

    const size_t hbase = (size_t)(b * E_ + e) * (C_ * (size_t)H_);
    #pragma unroll
    for (int n = 0; n < 4; ++n) {
        const int col = n0 + wn * 64 + n * 16 + l15;
        const float bias = b1[e * H_ + col];
        #pragma unroll
        for (int m = 0; m < 4; ++m) {
            const int rb = m0 + wm * 64 + m * 16 + lk * 4;
            #pragma unroll
            for (int r = 0; r < 4; ++r) {
                float h = acc[m][n][r] + bias;
                float g = 0.5f * h * (1.0f + erff(h * 0.70710678118f));
                Hbuf[hbase + (size_t)(rb + r) * H_ + col] = f2bf(g);
            }
        }
    }
}

__global__ __launch_bounds__(256) void gemm2_atomic(
    const u16* __restrict__ Hbuf, const u16* __restrict__ W2bf,
    const float* __restrict__ b2, const int* __restrict__ idx,
    const float* __restrict__ gate, float* __restrict__ out)
{
    const int mt = blockIdx.x >> 4, nt = blockIdx.x & 15;
    const int be = blockIdx.y;
    const int b = be >> 3, e = be & 7;
    const int m0 = mt * 128, n0 = nt * 128;

    __shared__ __align__(16) u16 As[128][72];
    __shared__ __align__(16) u16 Bs[128][72];

    const int tid = threadIdx.x;
    const int lane = tid & 63, wid = tid >> 6;
    const int wm = wid >> 1, wn = wid & 1;
    const int l15 = lane & 15, lk = lane >> 4;
    const int sr = tid >> 1;
    const int sh = (tid & 1) * 32;

    const u16* aSrc = Hbuf + ((size_t)(b * E_ + e) * C_ + m0 + sr) * H_ + sh;
    const u16* bSrc = W2bf + ((size_t)e * D_ + n0 + sr) * H_ + sh;

    f32x4 acc[4][4];
    #pragma unroll
    for (int i = 0; i < 4; ++i)
        #pragma unroll
        for (int j = 0; j < 4; ++j)
            acc[i][j] = (f32x4){0.f, 0.f, 0.f, 0.f};

    for (int k0 = 0; k0 < H_; k0 += 64) {
        __syncthreads();
        #pragma unroll
        for (int j = 0; j < 4; ++j) {
            *reinterpret_cast<short8*>(&As[sr][sh + j * 8]) =
                *reinterpret_cast<const short8*>(aSrc + k0 + j * 8);
            *reinterpret_cast<short8*>(&Bs[sr][sh + j * 8]) =
                *reinterpret_cast<const short8*>(bSrc + k0 + j * 8);
        }
        __syncthreads();
        #pragma unroll
        for (int kk = 0; kk < 64; kk += 32) {
            short8 af[4], bfr[4];
            #pragma unroll
            for (int m = 0; m < 4; ++m)
                af[m] = *reinterpret_cast<const short8*>(
                    &As[wm * 64 + m * 16 + l15][kk + lk * 8]);
            #pragma unroll
            for (int n = 0; n < 4; ++n)
                bfr[n] = *reinterpret_cast<const short8*>(
                    &Bs[wn * 64 + n * 16 + l15][kk + lk * 8]);
            #pragma unroll
            for (int m = 0; m < 4; ++m)
                #pragma unroll
                for (int n = 0; n < 4; ++n)
                    acc[m][n] = __builtin_amdgcn_mfma_f32_16x16x32_bf16(
                        af[m], bfr[n], acc[m][n], 0, 0, 0);
        }
    }

    const int ibase = (b * E_ + e) * C_ + m0 + wm * 64;
    #pragma unroll
    for (int m = 0; m < 4; ++m) {
        #pragma unroll
        for (int r = 0; r < 4; ++r) {
            const int c = m * 16 + lk * 4 + r;
            const int tok = idx[ibase + c];
            const float g = gate[ibase + c];
            float* orow = out + ((size_t)b * T_ + tok) * D_ + n0 + wn * 64;
            #pragma unroll
            for (int n = 0; n < 4; ++n) {
                const int col = n * 16 + l15;
                const float v = (acc[m][n][r] + b2[n0 + wn * 64 + col]) * g;
                atomicAdd(orow + col, v);
            }
        }
    }
}

extern "C" void kernel_launch(void* const* d_in, const int* in_sizes, int n_in,
                              void* d_out, int out_size, void* d_ws, size_t ws_size,
                              hipStream_t stream) {
    const float* x    = (const float*)d_in[0];
    const float* W1   = (const float*)d_in[1];
    const float* b1   = (const float*)d_in[2];
    const float* W2   = (const float*)d_in[3];
    const float* b2   = (const float*)d_in[4];
    const int*   idx  = (const int*)d_in[5];
    const float* gate = (const float*)d_in[6];
    float* out = (float*)d_out;

    const size_t nW = (size_t)E_ * H_ * D_;        // 4,194,304
    const size_t nX = (size_t)B_ * T_ * D_;        // 33,554,432
    const size_t nH = (size_t)B_ * E_ * C_ * H_;   // 8,388,608
    const size_t nY = (size_t)B_ * E_ * C_ * D_;   // 67,108,864
    const size_t needed = 2 * (2 * nW + nX + nH + nY)
                        + 4 * ((size_t)B_ * T_ * (1 + SLOTCAP));

    if (ws_size >= needed) {
        u16* W1bf = (u16*)d_ws;
        u16* W2bf = W1bf + nW;
        u16* xbf  = W2bf + nW;
        u16* Hbuf = xbf + nX;
        u16* Ybuf = Hbuf + nH;
        int* cnt   = (int*)(Ybuf + nY);
        int* slots = cnt + (size_t)B_ * T_;

        hipMemsetAsync(cnt, 0, (size_t)B_ * T_ * sizeof(int), stream);
        conv_f32_bf16<<<(int)(nW / 1024), 256, 0, stream>>>(W1, W1bf, (int)nW);
        conv_f32_bf16<<<(int)(nW / 1024), 256, 0, stream>>>(W2, W2bf, (int)nW);
        conv_f32_bf16<<<(int)(nX / 1024), 256, 0, stream>>>(x, xbf, (int)nX);
        fill_kernel<<<(B_ * E_ * C_) / 256, 256, 0, stream>>>(idx, cnt, slots);

        gemm1_bf<<<dim3(16, 32), 256, 0, stream>>>(xbf, W1bf, b1, idx, Hbuf);
        gemm2_y<<<dim3(128, 32), 256, 0, stream>>>(Hbuf, W2bf, b2, gate, Ybuf);
        combine_kernel<<<B_ * T_, 256, 0, stream>>>(Ybuf, cnt, slots, out);
    } else {
        // fallback: round-1 path (needs ~33.6 MB ws)
        u16* W1bf = (u16*)d_ws;
        u16* W2bf = W1bf + nW;
        u16* Hbuf = W2bf + nW;

        hipMemsetAsync(d_out, 0, (size_t)B_ * T_ * D_ * sizeof(float), stream);
        conv_f32_bf16<<<(int)(nW / 1024), 256, 0, stream>>>(W1, W1bf, (int)nW);
        conv_f32_bf16<<<(int)(nW / 1024), 256, 0, stream>>>(W2, W2bf, (int)nW);
        gemm1_f32<<<dim3(16, 32), 256, 0, stream>>>(x, W1bf, b1, idx, Hbuf);
        gemm2_atomic<<<dim3(128, 32), 256, 0, stream>>>(Hbuf, W2bf, b2, idx, gate, out);
    }
}

// Round 3
// 262.218 us; speedup vs baseline: 1.5379x; 1.1103x over previous
//
#include <hip/hip_runtime.h>
#include <math.h>

#define B_ 4
#define T_ 4096
#define D_ 2048
#define E_ 8
#define C_ 1024
#define H_ 256
#define SLOTCAP 32

typedef unsigned short u16;
typedef unsigned long long u64;
typedef __attribute__((ext_vector_type(8))) short short8;
typedef __attribute__((ext_vector_type(4))) float f32x4;

__device__ __forceinline__ u16 f2bf(float f) {
    union { float f; unsigned u; } v; v.f = f;
    unsigned r = (v.u + 0x7FFFu + ((v.u >> 16) & 1u)) >> 16;
    return (u16)r;
}
__device__ __forceinline__ float bf2f(u16 u) {
    union { unsigned u; float f; } v; v.u = ((unsigned)u) << 16;
    return v.f;
}

// swizzled u16 index into a [128][64] tile: chunk (8 u16) XOR'd by row&7
__device__ __forceinline__ int swz(int row, int chunk) {
    return (row << 6) + (((chunk ^ (row & 7)) << 3));
}

// ---------------- f32 -> bf16 conversion ----------------
__global__ __launch_bounds__(256) void conv_f32_bf16(
    const float* __restrict__ src, u16* __restrict__ dst, int n)
{
    int i = (blockIdx.x * 256 + threadIdx.x) * 4;
    if (i >= n) return;
    f32x4 v = *reinterpret_cast<const f32x4*>(src + i);
    u16 o[4];
    o[0] = f2bf(v[0]); o[1] = f2bf(v[1]); o[2] = f2bf(v[2]); o[3] = f2bf(v[3]);
    *reinterpret_cast<u64*>(dst + i) = *reinterpret_cast<const u64*>(o);
}

// ---------------- GEMM1: h = gelu(sel @ W1^T + b1) -> Hbuf bf16 ----------------
__global__ __launch_bounds__(256) void gemm1_bf(
    const u16* __restrict__ xbf, const u16* __restrict__ W1bf,
    const float* __restrict__ b1, const int* __restrict__ idx,
    u16* __restrict__ Hbuf)
{
    const int bt = blockIdx.x;          // 0..15 = mt*2 + nt
    const int mt = bt >> 1, nt = bt & 1;
    const int be = blockIdx.y;          // 0..31
    const int b = be >> 3, e = be & 7;
    const int m0 = mt * 128, n0 = nt * 128;

    __shared__ __align__(16) u16 As[128 * 64];
    __shared__ __align__(16) u16 Bs[128 * 64];
    __shared__ int toks[128];
    __shared__ float bs1[128];

    const int tid = threadIdx.x;
    if (tid < 128) {
        toks[tid] = idx[(b * E_ + e) * C_ + m0 + tid];
        bs1[tid] = b1[e * H_ + n0 + tid];
    }
    __syncthreads();

    const int lane = tid & 63, wid = tid >> 6;
    const int wm = wid >> 1, wn = wid & 1;
    const int l15 = lane & 15, lk = lane >> 4;

    const int sr = tid >> 1;            // staging row 0..127
    const int scb = (tid & 1) * 4;      // staging chunk base 0 or 4
    const int sh = scb * 8;             // col base in elements

    const u16* aSrc = xbf + (size_t)b * (T_ * (size_t)D_)
                          + (size_t)toks[sr] * D_ + sh;
    const u16* bSrc = W1bf + ((size_t)e * H_ + n0 + sr) * D_ + sh;

    int wOff[4];
    #pragma unroll
    for (int j = 0; j < 4; ++j) wOff[j] = swz(sr, scb + j);

    f32x4 acc[4][4];
    #pragma unroll
    for (int i = 0; i < 4; ++i)
        #pragma unroll
        for (int j = 0; j < 4; ++j)
            acc[i][j] = (f32x4){0.f, 0.f, 0.f, 0.f};

    short8 rA[4], rB[4];
    #pragma unroll
    for (int j = 0; j < 4; ++j) {
        rA[j] = *reinterpret_cast<const short8*>(aSrc + j * 8);
        rB[j] = *reinterpret_cast<const short8*>(bSrc + j * 8);
    }
    #pragma unroll
    for (int j = 0; j < 4; ++j) {
        *reinterpret_cast<short8*>(&As[wOff[j]]) = rA[j];
        *reinterpret_cast<short8*>(&Bs[wOff[j]]) = rB[j];
    }
    __syncthreads();

    const int NT = D_ / 64;  // 32
    for (int t = 0; t < NT; ++t) {
        if (t + 1 < NT) {
            #pragma unroll
            for (int j = 0; j < 4; ++j) {
                rA[j] = *reinterpret_cast<const short8*>(aSrc + (t + 1) * 64 + j * 8);
                rB[j] = *reinterpret_cast<const short8*>(bSrc + (t + 1) * 64 + j * 8);
            }
        }
        #pragma unroll
        for (int kk = 0; kk < 2; ++kk) {
            short8 af[4], bfr[4];
            #pragma unroll
            for (int m = 0; m < 4; ++m) {
                const int row = wm * 64 + m * 16 + l15;
                af[m] = *reinterpret_cast<const short8*>(&As[swz(row, kk * 4 + lk)]);
            }
            #pragma unroll
            for (int n = 0; n < 4; ++n) {
                const int row = wn * 64 + n * 16 + l15;
                bfr[n] = *reinterpret_cast<const short8*>(&Bs[swz(row, kk * 4 + lk)]);
            }
            // swapped operands: D col(lane&15)=c(A rows), D row(lk*4+r)=h(B rows)
            #pragma unroll
            for (int m = 0; m < 4; ++m)
                #pragma unroll
                for (int n = 0; n < 4; ++n)
                    acc[m][n] = __builtin_amdgcn_mfma_f32_16x16x32_bf16(
                        bfr[n], af[m], acc[m][n], 0, 0, 0);
        }
        if (t + 1 < NT) {
            __syncthreads();
            #pragma unroll
            for (int j = 0; j < 4; ++j) {
                *reinterpret_cast<short8*>(&As[wOff[j]]) = rA[j];
                *reinterpret_cast<short8*>(&Bs[wOff[j]]) = rB[j];
            }
            __syncthreads();
        }
    }

    // epilogue: bias + exact gelu, 8B packed stores
    const size_t hbase = (size_t)(b * E_ + e) * (C_ * (size_t)H_);
    #pragma unroll
    for (int m = 0; m < 4; ++m) {
        const int cl = wm * 64 + m * 16 + l15;          // Hbuf row (c)
        const size_t rowoff = hbase + (size_t)(m0 + cl) * H_ + n0;
        #pragma unroll
        for (int n = 0; n < 4; ++n) {
            const int hb = wn * 64 + n * 16 + lk * 4;   // h col base
            u16 o[4];
            #pragma unroll
            for (int r = 0; r < 4; ++r) {
                float h = acc[m][n][r] + bs1[hb + r];
                float g = 0.5f * h * (1.0f + erff(h * 0.70710678118f));
                o[r] = f2bf(g);
            }
            *reinterpret_cast<u64*>(&Hbuf[rowoff + hb]) =
                *reinterpret_cast<const u64*>(o);
        }
    }
}

// ---------------- GEMM2: Ybuf = ((h @ W2^T) + b2) * gate  (bf16) ----------------
__global__ __launch_bounds__(256) void gemm2_y(
    const u16* __restrict__ Hbuf, const u16* __restrict__ W2bf,
    const float* __restrict__ b2, const float* __restrict__ gate,
    u16* __restrict__ Ybuf)
{
    const int mt = blockIdx.x >> 4, nt = blockIdx.x & 15;
    const int be = blockIdx.y;
    const int b = be >> 3, e = be & 7;
    const int m0 = mt * 128, n0 = nt * 128;

    __shared__ __align__(16) u16 As[128 * 64];
    __shared__ __align__(16) u16 Bs[128 * 64];
    __shared__ float gs[128];
    __shared__ float bs2[128];

    const int tid = threadIdx.x;
    if (tid < 128) {
        gs[tid] = gate[(b * E_ + e) * C_ + m0 + tid];
        bs2[tid] = b2[n0 + tid];
    }
    __syncthreads();

    const int lane = tid & 63, wid = tid >> 6;
    const int wm = wid >> 1, wn = wid & 1;
    const int l15 = lane & 15, lk = lane >> 4;

    const int sr = tid >> 1;
    const int scb = (tid & 1) * 4;
    const int sh = scb * 8;

    const u16* aSrc = Hbuf + ((size_t)(b * E_ + e) * C_ + m0 + sr) * H_ + sh;
    const u16* bSrc = W2bf + ((size_t)e * D_ + n0 + sr) * H_ + sh;

    int wOff[4];
    #pragma unroll
    for (int j = 0; j < 4; ++j) wOff[j] = swz(sr, scb + j);

    f32x4 acc[4][4];
    #pragma unroll
    for (int i = 0; i < 4; ++i)
        #pragma unroll
        for (int j = 0; j < 4; ++j)
            acc[i][j] = (f32x4){0.f, 0.f, 0.f, 0.f};

    short8 rA[4], rB[4];
    #pragma unroll
    for (int j = 0; j < 4; ++j) {
        rA[j] = *reinterpret_cast<const short8*>(aSrc + j * 8);
        rB[j] = *reinterpret_cast<const short8*>(bSrc + j * 8);
    }
    #pragma unroll
    for (int j = 0; j < 4; ++j) {
        *reinterpret_cast<short8*>(&As[wOff[j]]) = rA[j];
        *reinterpret_cast<short8*>(&Bs[wOff[j]]) = rB[j];
    }
    __syncthreads();

    const int NT = H_ / 64;  // 4
    for (int t = 0; t < NT; ++t) {
        if (t + 1 < NT) {
            #pragma unroll
            for (int j = 0; j < 4; ++j) {
                rA[j] = *reinterpret_cast<const short8*>(aSrc + (t + 1) * 64 + j * 8);
                rB[j] = *reinterpret_cast<const short8*>(bSrc + (t + 1) * 64 + j * 8);
            }
        }
        #pragma unroll
        for (int kk = 0; kk < 2; ++kk) {
            short8 af[4], bfr[4];
            #pragma unroll
            for (int m = 0; m < 4; ++m) {
                const int row = wm * 64 + m * 16 + l15;
                af[m] = *reinterpret_cast<const short8*>(&As[swz(row, kk * 4 + lk)]);
            }
            #pragma unroll
            for (int n = 0; n < 4; ++n) {
                const int row = wn * 64 + n * 16 + l15;
                bfr[n] = *reinterpret_cast<const short8*>(&Bs[swz(row, kk * 4 + lk)]);
            }
            #pragma unroll
            for (int m = 0; m < 4; ++m)
                #pragma unroll
                for (int n = 0; n < 4; ++n)
                    acc[m][n] = __builtin_amdgcn_mfma_f32_16x16x32_bf16(
                        bfr[n], af[m], acc[m][n], 0, 0, 0);
        }
        if (t + 1 < NT) {
            __syncthreads();
            #pragma unroll
            for (int j = 0; j < 4; ++j) {
                *reinterpret_cast<short8*>(&As[wOff[j]]) = rA[j];
                *reinterpret_cast<short8*>(&Bs[wOff[j]]) = rB[j];
            }
            __syncthreads();
        }
    }

    // epilogue: (acc + b2) * gate -> bf16 Ybuf, 8B packed stores
    const size_t ybase = (size_t)(b * E_ + e) * C_ + m0;
    #pragma unroll
    for (int m = 0; m < 4; ++m) {
        const int cl = wm * 64 + m * 16 + l15;          // Ybuf row (c)
        const float g = gs[cl];
        u16* rowp = Ybuf + (ybase + cl) * (size_t)D_ + n0;
        #pragma unroll
        for (int n = 0; n < 4; ++n) {
            const int db = wn * 64 + n * 16 + lk * 4;   // d col base
            u16 o[4];
            #pragma unroll
            for (int r = 0; r < 4; ++r)
                o[r] = f2bf((acc[m][n][r] + bs2[db + r]) * g);
            *reinterpret_cast<u64*>(rowp + db) =
                *reinterpret_cast<const u64*>(o);
        }
    }
}

// ---------------- inverted index build ----------------
__global__ __launch_bounds__(256) void fill_kernel(
    const int* __restrict__ idx, int* __restrict__ cnt,
    int* __restrict__ slots)
{
    int i = blockIdx.x * 256 + threadIdx.x;
    if (i >= B_ * E_ * C_) return;
    int b = i / (E_ * C_);
    int slot = i % (E_ * C_);
    int t = idx[i];
    int p = atomicAdd(&cnt[b * T_ + t], 1);
    if (p < SLOTCAP) slots[(b * T_ + t) * SLOTCAP + p] = slot;
}

// ---------------- combine: out[b,t,:] = sum over slots of Ybuf ----------------
__global__ __launch_bounds__(256) void combine_kernel(
    const u16* __restrict__ Ybuf, const int* __restrict__ cnt,
    const int* __restrict__ slots, float* __restrict__ out)
{
    const int bt = blockIdx.x;               // b*T_ + t
    const int tid = threadIdx.x;
    __shared__ int sl[SLOTCAP];
    int n = cnt[bt];
    n = n > SLOTCAP ? SLOTCAP : n;
    if (tid < n) sl[tid] = slots[bt * SLOTCAP + tid];
    __syncthreads();
    const int b = bt >> 12;                  // T_ = 4096
    float a[8] = {0.f, 0.f, 0.f, 0.f, 0.f, 0.f, 0.f, 0.f};
    for (int s = 0; s < n; ++s) {
        const u16* yrow = Ybuf + ((size_t)b * (E_ * C_) + sl[s]) * D_ + tid * 8;
        short8 v = *reinterpret_cast<const short8*>(yrow);
        #pragma unroll
        for (int j = 0; j < 8; ++j) a[j] += bf2f((u16)v[j]);
    }
    float* orow = out + (size_t)bt * D_ + tid * 8;
    *reinterpret_cast<f32x4*>(orow)     = (f32x4){a[0], a[1], a[2], a[3]};
    *reinterpret_cast<f32x4*>(orow + 4) = (f32x4){a[4], a[5], a[6], a[7]};
}

extern "C" void kernel_launch(void* const* d_in, const int* in_sizes, int n_in,
                              void* d_out, int out_size, void* d_ws, size_t ws_size,
                              hipStream_t stream) {
    const float* x    = (const float*)d_in[0];
    const float* W1   = (const float*)d_in[1];
    const float* b1   = (const float*)d_in[2];
    const float* W2   = (const float*)d_in[3];
    const float* b2   = (const float*)d_in[4];
    const int*   idx  = (const int*)d_in[5];
    const float* gate = (const float*)d_in[6];
    float* out = (float*)d_out;

    const size_t nW = (size_t)E_ * H_ * D_;        // 4,194,304
    const size_t nX = (size_t)B_ * T_ * D_;        // 33,554,432
    const size_t nH = (size_t)B_ * E_ * C_ * H_;   // 8,388,608
    const size_t nY = (size_t)B_ * E_ * C_ * D_;   // 67,108,864

    u16* W1bf = (u16*)d_ws;
    u16* W2bf = W1bf + nW;
    u16* xbf  = W2bf + nW;
    u16* Hbuf = xbf + nX;
    u16* Ybuf = Hbuf + nH;
    int* cnt   = (int*)(Ybuf + nY);
    int* slots = cnt + (size_t)B_ * T_;

    hipMemsetAsync(cnt, 0, (size_t)B_ * T_ * sizeof(int), stream);
    conv_f32_bf16<<<(int)(nW / 1024), 256, 0, stream>>>(W1, W1bf, (int)nW);
    conv_f32_bf16<<<(int)(nW / 1024), 256, 0, stream>>>(W2, W2bf, (int)nW);
    conv_f32_bf16<<<(int)(nX / 1024), 256, 0, stream>>>(x, xbf, (int)nX);
    fill_kernel<<<(B_ * E_ * C_) / 256, 256, 0, stream>>>(idx, cnt, slots);

    gemm1_bf<<<dim3(16, 32), 256, 0, stream>>>(xbf, W1bf, b1, idx, Hbuf);
    gemm2_y<<<dim3(128, 32), 256, 0, stream>>>(Hbuf, W2bf, b2, gate, Ybuf);
    combine_kernel<<<B_ * T_, 256, 0, stream>>>(Ybuf, cnt, slots, out);
}

// Round 4
// 244.323 us; speedup vs baseline: 1.6506x; 1.0732x over previous
//
#include <hip/hip_runtime.h>
#include <math.h>

#define B_ 4
#define T_ 4096
#define D_ 2048
#define E_ 8
#define C_ 1024
#define H_ 256
#define SLOTCAP 32

typedef unsigned short u16;
typedef unsigned long long u64;
typedef __attribute__((ext_vector_type(8))) short short8;
typedef __attribute__((ext_vector_type(4))) float f32x4;

__device__ __forceinline__ u16 f2bf(float f) {
    union { float f; unsigned u; } v; v.f = f;
    unsigned r = (v.u + 0x7FFFu + ((v.u >> 16) & 1u)) >> 16;
    return (u16)r;
}
__device__ __forceinline__ float bf2f(u16 u) {
    union { unsigned u; float f; } v; v.u = ((unsigned)u) << 16;
    return v.f;
}

// swizzled u16 index into a [rows][64] tile: 8-u16 chunk XOR'd by row&7
__device__ __forceinline__ int swz(int row, int chunk) {
    return (row << 6) + ((chunk ^ (row & 7)) << 3);
}

// ---------------- f32 -> bf16 conversion (weights only) ----------------
__global__ __launch_bounds__(256) void conv_f32_bf16(
    const float* __restrict__ src, u16* __restrict__ dst, int n)
{
    int i = (blockIdx.x * 256 + threadIdx.x) * 4;
    if (i >= n) return;
    f32x4 v = *reinterpret_cast<const f32x4*>(src + i);
    u16 o[4];
    o[0] = f2bf(v[0]); o[1] = f2bf(v[1]); o[2] = f2bf(v[2]); o[3] = f2bf(v[3]);
    *reinterpret_cast<u64*>(dst + i) = *reinterpret_cast<const u64*>(o);
}

// ---------------- GEMM1: Hbuf = gelu(sel @ W1^T + b1) ----------------
// tile: 128 c-rows x 256 h-cols (full H), K=2048, 512 threads (8 waves 2Mx4N)
__global__ __launch_bounds__(512) void gemm1_v2(
    const float* __restrict__ x, const u16* __restrict__ W1bf,
    const float* __restrict__ b1, const int* __restrict__ idx,
    u16* __restrict__ Hbuf)
{
    const int mt = blockIdx.x;          // 0..7
    const int be = blockIdx.y;          // 0..31
    const int b = be >> 3, e = be & 7;
    const int m0 = mt * 128;

    __shared__ __align__(16) u16 As[128 * 64];
    __shared__ __align__(16) u16 Bs[256 * 64];
    __shared__ int toks[128];
    __shared__ float bs1[256];

    const int tid = threadIdx.x;
    if (tid < 128) toks[tid] = idx[(b * E_ + e) * C_ + m0 + tid];
    if (tid < 256) bs1[tid] = b1[e * H_ + tid];
    __syncthreads();

    const int lane = tid & 63, wid = tid >> 6;
    const int wm = wid >> 2, wn = wid & 3;
    const int l15 = lane & 15, lk = lane >> 4;

    // A staging: row ar (0..127), chunks ac0 and ac0+4 (f32 source, cvt here)
    const int ar = tid >> 2, ac0 = tid & 3;
    const float* aRow = x + (size_t)b * (T_ * (size_t)D_)
                          + (size_t)toks[ar] * D_;
    // B staging: row br (0..255), chunks bc0..bc0+3 (bf16 source)
    const int br = tid >> 1, bc0 = (tid & 1) * 4;
    const u16* bRow = W1bf + ((size_t)e * H_ + br) * D_;

    const int aOff0 = swz(ar, ac0), aOff1 = swz(ar, ac0 + 4);
    int bOff[4];
    #pragma unroll
    for (int j = 0; j < 4; ++j) bOff[j] = swz(br, bc0 + j);

    f32x4 acc[4][4];
    #pragma unroll
    for (int i = 0; i < 4; ++i)
        #pragma unroll
        for (int j = 0; j < 4; ++j)
            acc[i][j] = (f32x4){0.f, 0.f, 0.f, 0.f};

    f32x4 pa[4];        // chunk0 lo/hi, chunk1 lo/hi
    short8 pb[4];

    // prologue: tile 0
    pa[0] = *reinterpret_cast<const f32x4*>(aRow + ac0 * 8);
    pa[1] = *reinterpret_cast<const f32x4*>(aRow + ac0 * 8 + 4);
    pa[2] = *reinterpret_cast<const f32x4*>(aRow + (ac0 + 4) * 8);
    pa[3] = *reinterpret_cast<const f32x4*>(aRow + (ac0 + 4) * 8 + 4);
    #pragma unroll
    for (int j = 0; j < 4; ++j)
        pb[j] = *reinterpret_cast<const short8*>(bRow + (bc0 + j) * 8);
    {
        short8 s0, s1;
        #pragma unroll
        for (int r = 0; r < 4; ++r) {
            s0[r] = (short)f2bf(pa[0][r]); s0[r + 4] = (short)f2bf(pa[1][r]);
            s1[r] = (short)f2bf(pa[2][r]); s1[r + 4] = (short)f2bf(pa[3][r]);
        }
        *reinterpret_cast<short8*>(&As[aOff0]) = s0;
        *reinterpret_cast<short8*>(&As[aOff1]) = s1;
        #pragma unroll
        for (int j = 0; j < 4; ++j)
            *reinterpret_cast<short8*>(&Bs[bOff[j]]) = pb[j];
    }
    __syncthreads();

    const int NT = D_ / 64;  // 32
    for (int t = 0; t < NT; ++t) {
        if (t + 1 < NT) {
            const int k = (t + 1) * 64;
            pa[0] = *reinterpret_cast<const f32x4*>(aRow + k + ac0 * 8);
            pa[1] = *reinterpret_cast<const f32x4*>(aRow + k + ac0 * 8 + 4);
            pa[2] = *reinterpret_cast<const f32x4*>(aRow + k + (ac0 + 4) * 8);
            pa[3] = *reinterpret_cast<const f32x4*>(aRow + k + (ac0 + 4) * 8 + 4);
            #pragma unroll
            for (int j = 0; j < 4; ++j)
                pb[j] = *reinterpret_cast<const short8*>(bRow + k + (bc0 + j) * 8);
        }
        #pragma unroll
        for (int kk = 0; kk < 2; ++kk) {
            short8 af[4], bfr[4];
            #pragma unroll
            for (int m = 0; m < 4; ++m) {
                const int row = wm * 64 + m * 16 + l15;
                af[m] = *reinterpret_cast<const short8*>(&As[swz(row, kk * 4 + lk)]);
            }
            #pragma unroll
            for (int n = 0; n < 4; ++n) {
                const int row = wn * 64 + n * 16 + l15;
                bfr[n] = *reinterpret_cast<const short8*>(&Bs[swz(row, kk * 4 + lk)]);
            }
            #pragma unroll
            for (int m = 0; m < 4; ++m)
                #pragma unroll
                for (int n = 0; n < 4; ++n)
                    acc[m][n] = __builtin_amdgcn_mfma_f32_16x16x32_bf16(
                        bfr[n], af[m], acc[m][n], 0, 0, 0);
        }
        if (t + 1 < NT) {
            __syncthreads();
            short8 s0, s1;
            #pragma unroll
            for (int r = 0; r < 4; ++r) {
                s0[r] = (short)f2bf(pa[0][r]); s0[r + 4] = (short)f2bf(pa[1][r]);
                s1[r] = (short)f2bf(pa[2][r]); s1[r + 4] = (short)f2bf(pa[3][r]);
            }
            *reinterpret_cast<short8*>(&As[aOff0]) = s0;
            *reinterpret_cast<short8*>(&As[aOff1]) = s1;
            #pragma unroll
            for (int j = 0; j < 4; ++j)
                *reinterpret_cast<short8*>(&Bs[bOff[j]]) = pb[j];
            __syncthreads();
        }
    }

    // epilogue: bias + exact gelu, packed 8B stores
    const size_t hbase = ((size_t)(b * E_ + e) * C_ + m0) * H_;
    #pragma unroll
    for (int m = 0; m < 4; ++m) {
        const int cl = wm * 64 + m * 16 + l15;
        u16* rowp = Hbuf + hbase + (size_t)cl * H_;
        #pragma unroll
        for (int n = 0; n < 4; ++n) {
            const int hb = wn * 64 + n * 16 + lk * 4;
            u16 o[4];
            #pragma unroll
            for (int r = 0; r < 4; ++r) {
                float h = acc[m][n][r] + bs1[hb + r];
                float g = 0.5f * h * (1.0f + erff(h * 0.70710678118f));
                o[r] = f2bf(g);
            }
            *reinterpret_cast<u64*>(rowp + hb) = *reinterpret_cast<const u64*>(o);
        }
    }
}

// ---------------- GEMM2: Ybuf = ((Hbuf @ W2^T) + b2) * gate ----------------
// tile: 128 c-rows x 256 d-cols, K=256, 512 threads (8 waves 2Mx4N)
__global__ __launch_bounds__(512) void gemm2_v2(
    const u16* __restrict__ Hbuf, const u16* __restrict__ W2bf,
    const float* __restrict__ b2, const float* __restrict__ gate,
    u16* __restrict__ Ybuf)
{
    const int mt = blockIdx.x >> 3, nt = blockIdx.x & 7;
    const int be = blockIdx.y;
    const int b = be >> 3, e = be & 7;
    const int m0 = mt * 128, n0 = nt * 256;

    __shared__ __align__(16) u16 As[128 * 64];
    __shared__ __align__(16) u16 Bs[256 * 64];
    __shared__ float gs[128];
    __shared__ float bs2[256];

    const int tid = threadIdx.x;
    if (tid < 128) gs[tid] = gate[(b * E_ + e) * C_ + m0 + tid];
    if (tid < 256) bs2[tid] = b2[n0 + tid];
    __syncthreads();

    const int lane = tid & 63, wid = tid >> 6;
    const int wm = wid >> 2, wn = wid & 3;
    const int l15 = lane & 15, lk = lane >> 4;

    const int ar = tid >> 2, ac0 = tid & 3;
    const u16* aRow = Hbuf + ((size_t)(b * E_ + e) * C_ + m0 + ar) * H_;
    const int br = tid >> 1, bc0 = (tid & 1) * 4;
    const u16* bRow = W2bf + ((size_t)e * D_ + n0 + br) * H_;

    const int aOff0 = swz(ar, ac0), aOff1 = swz(ar, ac0 + 4);
    int bOff[4];
    #pragma unroll
    for (int j = 0; j < 4; ++j) bOff[j] = swz(br, bc0 + j);

    f32x4 acc[4][4];
    #pragma unroll
    for (int i = 0; i < 4; ++i)
        #pragma unroll
        for (int j = 0; j < 4; ++j)
            acc[i][j] = (f32x4){0.f, 0.f, 0.f, 0.f};

    short8 pa0, pa1, pb[4];
    pa0 = *reinterpret_cast<const short8*>(aRow + ac0 * 8);
    pa1 = *reinterpret_cast<const short8*>(aRow + (ac0 + 4) * 8);
    #pragma unroll
    for (int j = 0; j < 4; ++j)
        pb[j] = *reinterpret_cast<const short8*>(bRow + (bc0 + j) * 8);
    *reinterpret_cast<short8*>(&As[aOff0]) = pa0;
    *reinterpret_cast<short8*>(&As[aOff1]) = pa1;
    #pragma unroll
    for (int j = 0; j < 4; ++j)
        *reinterpret_cast<short8*>(&Bs[bOff[j]]) = pb[j];
    __syncthreads();

    const int NT = H_ / 64;  // 4
    for (int t = 0; t < NT; ++t) {
        if (t + 1 < NT) {
            const int k = (t + 1) * 64;
            pa0 = *reinterpret_cast<const short8*>(aRow + k + ac0 * 8);
            pa1 = *reinterpret_cast<const short8*>(aRow + k + (ac0 + 4) * 8);
            #pragma unroll
            for (int j = 0; j < 4; ++j)
                pb[j] = *reinterpret_cast<const short8*>(bRow + k + (bc0 + j) * 8);
        }
        #pragma unroll
        for (int kk = 0; kk < 2; ++kk) {
            short8 af[4], bfr[4];
            #pragma unroll
            for (int m = 0; m < 4; ++m) {
                const int row = wm * 64 + m * 16 + l15;
                af[m] = *reinterpret_cast<const short8*>(&As[swz(row, kk * 4 + lk)]);
            }
            #pragma unroll
            for (int n = 0; n < 4; ++n) {
                const int row = wn * 64 + n * 16 + l15;
                bfr[n] = *reinterpret_cast<const short8*>(&Bs[swz(row, kk * 4 + lk)]);
            }
            #pragma unroll
            for (int m = 0; m < 4; ++m)
                #pragma unroll
                for (int n = 0; n < 4; ++n)
                    acc[m][n] = __builtin_amdgcn_mfma_f32_16x16x32_bf16(
                        bfr[n], af[m], acc[m][n], 0, 0, 0);
        }
        if (t + 1 < NT) {
            __syncthreads();
            *reinterpret_cast<short8*>(&As[aOff0]) = pa0;
            *reinterpret_cast<short8*>(&As[aOff1]) = pa1;
            #pragma unroll
            for (int j = 0; j < 4; ++j)
                *reinterpret_cast<short8*>(&Bs[bOff[j]]) = pb[j];
            __syncthreads();
        }
    }

    // epilogue: (acc + b2) * gate -> bf16, packed 8B stores
    const size_t ybase = (size_t)(b * E_ + e) * C_ + m0;
    #pragma unroll
    for (int m = 0; m < 4; ++m) {
        const int cl = wm * 64 + m * 16 + l15;
        const float g = gs[cl];
        u16* rowp = Ybuf + (ybase + cl) * (size_t)D_ + n0;
        #pragma unroll
        for (int n = 0; n < 4; ++n) {
            const int db = wn * 64 + n * 16 + lk * 4;
            u16 o[4];
            #pragma unroll
            for (int r = 0; r < 4; ++r)
                o[r] = f2bf((acc[m][n][r] + bs2[db + r]) * g);
            *reinterpret_cast<u64*>(rowp + db) = *reinterpret_cast<const u64*>(o);
        }
    }
}

// ---------------- inverted index build ----------------
__global__ __launch_bounds__(256) void fill_kernel(
    const int* __restrict__ idx, int* __restrict__ cnt,
    int* __restrict__ slots)
{
    int i = blockIdx.x * 256 + threadIdx.x;
    if (i >= B_ * E_ * C_) return;
    int b = i / (E_ * C_);
    int slot = i % (E_ * C_);
    int t = idx[i];
    int p = atomicAdd(&cnt[b * T_ + t], 1);
    if (p < SLOTCAP) slots[(b * T_ + t) * SLOTCAP + p] = slot;
}

// ---------------- combine: out[b,t,:] = sum over slots of Ybuf ----------------
__global__ __launch_bounds__(256) void combine_kernel(
    const u16* __restrict__ Ybuf, const int* __restrict__ cnt,
    const int* __restrict__ slots, float* __restrict__ out)
{
    const int bt = blockIdx.x;               // b*T_ + t
    const int tid = threadIdx.x;
    __shared__ int sl[SLOTCAP];
    int n = cnt[bt];
    n = n > SLOTCAP ? SLOTCAP : n;
    if (tid < n) sl[tid] = slots[bt * SLOTCAP + tid];
    __syncthreads();
    const int b = bt >> 12;                  // T_ = 4096
    float a[8] = {0.f, 0.f, 0.f, 0.f, 0.f, 0.f, 0.f, 0.f};
    for (int s = 0; s < n; ++s) {
        const u16* yrow = Ybuf + ((size_t)b * (E_ * C_) + sl[s]) * D_ + tid * 8;
        short8 v = *reinterpret_cast<const short8*>(yrow);
        #pragma unroll
        for (int j = 0; j < 8; ++j) a[j] += bf2f((u16)v[j]);
    }
    float* orow = out + (size_t)bt * D_ + tid * 8;
    *reinterpret_cast<f32x4*>(orow)     = (f32x4){a[0], a[1], a[2], a[3]};
    *reinterpret_cast<f32x4*>(orow + 4) = (f32x4){a[4], a[5], a[6], a[7]};
}

extern "C" void kernel_launch(void* const* d_in, const int* in_sizes, int n_in,
                              void* d_out, int out_size, void* d_ws, size_t ws_size,
                              hipStream_t stream) {
    const float* x    = (const float*)d_in[0];
    const float* W1   = (const float*)d_in[1];
    const float* b1   = (const float*)d_in[2];
    const float* W2   = (const float*)d_in[3];
    const float* b2   = (const float*)d_in[4];
    const int*   idx  = (const int*)d_in[5];
    const float* gate = (const float*)d_in[6];
    float* out = (float*)d_out;

    const size_t nW = (size_t)E_ * H_ * D_;        // 4,194,304
    const size_t nH = (size_t)B_ * E_ * C_ * H_;   // 8,388,608
    const size_t nY = (size_t)B_ * E_ * C_ * D_;   // 67,108,864

    u16* W1bf = (u16*)d_ws;
    u16* W2bf = W1bf + nW;
    u16* Hbuf = W2bf + nW;
    u16* Ybuf = Hbuf + nH;
    int* cnt   = (int*)(Ybuf + nY);
    int* slots = cnt + (size_t)B_ * T_;

    hipMemsetAsync(cnt, 0, (size_t)B_ * T_ * sizeof(int), stream);
    conv_f32_bf16<<<(int)(nW / 1024), 256, 0, stream>>>(W1, W1bf, (int)nW);
    conv_f32_bf16<<<(int)(nW / 1024), 256, 0, stream>>>(W2, W2bf, (int)nW);
    fill_kernel<<<(B_ * E_ * C_) / 256, 256, 0, stream>>>(idx, cnt, slots);

    gemm1_v2<<<dim3(8, 32), 512, 0, stream>>>(x, W1bf, b1, idx, Hbuf);
    gemm2_v2<<<dim3(64, 32), 512, 0, stream>>>(Hbuf, W2bf, b2, gate, Ybuf);
    combine_kernel<<<B_ * T_, 256, 0, stream>>>(Ybuf, cnt, slots, out);
}

// Round 5
// 218.996 us; speedup vs baseline: 1.8415x; 1.1157x over previous
//
#include <hip/hip_runtime.h>
#include <math.h>

#define B_ 4
#define T_ 4096
#define D_ 2048
#define E_ 8
#define C_ 1024
#define H_ 256
#define SLOTCAP 32

typedef unsigned short u16;
typedef unsigned long long u64;
typedef __attribute__((ext_vector_type(8))) short short8;
typedef __attribute__((ext_vector_type(4))) float f32x4;

__device__ __forceinline__ u16 f2bf(float f) {
    union { float f; unsigned u; } v; v.f = f;
    unsigned r = (v.u + 0x7FFFu + ((v.u >> 16) & 1u)) >> 16;
    return (u16)r;
}
__device__ __forceinline__ float bf2f(u16 u) {
    union { unsigned u; float f; } v; v.u = ((unsigned)u) << 16;
    return v.f;
}

// swizzled u16 index into a [rows][64] tile: 8-u16 chunk XOR'd by row&7
__device__ __forceinline__ int swz(int row, int chunk) {
    return (row << 6) + ((chunk ^ (row & 7)) << 3);
}

// ---------------- f32 -> bf16 conversion (weights only) ----------------
__global__ __launch_bounds__(256) void conv_f32_bf16(
    const float* __restrict__ src, u16* __restrict__ dst, int n)
{
    int i = (blockIdx.x * 256 + threadIdx.x) * 4;
    if (i >= n) return;
    f32x4 v = *reinterpret_cast<const f32x4*>(src + i);
    u16 o[4];
    o[0] = f2bf(v[0]); o[1] = f2bf(v[1]); o[2] = f2bf(v[2]); o[3] = f2bf(v[3]);
    *reinterpret_cast<u64*>(dst + i) = *reinterpret_cast<const u64*>(o);
}

// ---------------- GEMM1 v3: double-buffered LDS, 1 raw barrier per K-step --
// tile: 128 c-rows x 256 h-cols (full H), K=2048, 512 threads (8 waves 2Mx4N)
__global__ __launch_bounds__(512) void gemm1_v3(
    const float* __restrict__ x, const u16* __restrict__ W1bf,
    const float* __restrict__ b1, const int* __restrict__ idx,
    u16* __restrict__ Hbuf)
{
    const int mt = blockIdx.x;          // 0..7
    const int be = blockIdx.y;          // 0..31
    const int b = be >> 3, e = be & 7;
    const int m0 = mt * 128;

    __shared__ __align__(16) u16 As[2][128 * 64];
    __shared__ __align__(16) u16 Bs[2][256 * 64];
    __shared__ int toks[128];
    __shared__ float bs1[256];

    const int tid = threadIdx.x;
    if (tid < 128) toks[tid] = idx[(b * E_ + e) * C_ + m0 + tid];
    if (tid < 256) bs1[tid] = b1[e * H_ + tid];
    __syncthreads();

    const int lane = tid & 63, wid = tid >> 6;
    const int wm = wid >> 2, wn = wid & 3;
    const int l15 = lane & 15, lk = lane >> 4;

    // A staging: row ar (0..127), chunks ac0 / ac0+4 (f32 source, cvt here)
    const int ar = tid >> 2, ac0 = tid & 3;
    const float* aRow = x + (size_t)b * (T_ * (size_t)D_)
                          + (size_t)toks[ar] * D_;
    // B staging: row br (0..255), chunks bc0..bc0+3 (bf16 source)
    const int br = tid >> 1, bc0 = (tid & 1) * 4;
    const u16* bRow = W1bf + ((size_t)e * H_ + br) * D_;

    const int aOff0 = swz(ar, ac0), aOff1 = swz(ar, ac0 + 4);
    int bOff[4];
    #pragma unroll
    for (int j = 0; j < 4; ++j) bOff[j] = swz(br, bc0 + j);

    f32x4 acc[4][4];
    #pragma unroll
    for (int i = 0; i < 4; ++i)
        #pragma unroll
        for (int j = 0; j < 4; ++j)
            acc[i][j] = (f32x4){0.f, 0.f, 0.f, 0.f};

    f32x4 pa[4];
    short8 pb[4];

#define G1_LOAD(k)                                                            \
    do {                                                                      \
        pa[0] = *reinterpret_cast<const f32x4*>(aRow + (k) + ac0 * 8);        \
        pa[1] = *reinterpret_cast<const f32x4*>(aRow + (k) + ac0 * 8 + 4);    \
        pa[2] = *reinterpret_cast<const f32x4*>(aRow + (k) + (ac0 + 4) * 8);  \
        pa[3] = *reinterpret_cast<const f32x4*>(aRow + (k) + (ac0 + 4) * 8 + 4);\
        _Pragma("unroll")                                                     \
        for (int j = 0; j < 4; ++j)                                           \
            pb[j] = *reinterpret_cast<const short8*>(bRow + (k) + (bc0 + j) * 8);\
    } while (0)

#define G1_WRITE(buf)                                                         \
    do {                                                                      \
        short8 s0, s1;                                                        \
        _Pragma("unroll")                                                     \
        for (int r = 0; r < 4; ++r) {                                         \
            s0[r] = (short)f2bf(pa[0][r]); s0[r + 4] = (short)f2bf(pa[1][r]); \
            s1[r] = (short)f2bf(pa[2][r]); s1[r + 4] = (short)f2bf(pa[3][r]); \
        }                                                                     \
        *reinterpret_cast<short8*>(&As[buf][aOff0]) = s0;                     \
        *reinterpret_cast<short8*>(&As[buf][aOff1]) = s1;                     \
        _Pragma("unroll")                                                     \
        for (int j = 0; j < 4; ++j)                                           \
            *reinterpret_cast<short8*>(&Bs[buf][bOff[j]]) = pb[j];            \
    } while (0)

    // prologue: tile 0 into buf0; tile 1 into regs
    G1_LOAD(0);
    G1_WRITE(0);
    G1_LOAD(64);
    asm volatile("s_waitcnt lgkmcnt(0)" ::: "memory");
    __builtin_amdgcn_s_barrier();

    const int NT = D_ / 64;  // 32
    for (int t = 0; t < NT; ++t) {
        const int cur = t & 1;
        if (t + 1 < NT) G1_WRITE(cur ^ 1);     // t+1 data (regs), overlaps MFMA
        if (t + 2 < NT) G1_LOAD((t + 2) * 64); // stays in flight across barrier
        #pragma unroll
        for (int kk = 0; kk < 2; ++kk) {
            short8 af[4], bfr[4];
            #pragma unroll
            for (int m = 0; m < 4; ++m) {
                const int row = wm * 64 + m * 16 + l15;
                af[m] = *reinterpret_cast<const short8*>(
                    &As[cur][swz(row, kk * 4 + lk)]);
            }
            #pragma unroll
            for (int n = 0; n < 4; ++n) {
                const int row = wn * 64 + n * 16 + l15;
                bfr[n] = *reinterpret_cast<const short8*>(
                    &Bs[cur][swz(row, kk * 4 + lk)]);
            }
            #pragma unroll
            for (int m = 0; m < 4; ++m)
                #pragma unroll
                for (int n = 0; n < 4; ++n)
                    acc[m][n] = __builtin_amdgcn_mfma_f32_16x16x32_bf16(
                        bfr[n], af[m], acc[m][n], 0, 0, 0);
        }
        // own ds_writes + ds_reads done -> visible to all after barrier;
        // global loads (vmcnt) deliberately NOT drained here.
        asm volatile("s_waitcnt lgkmcnt(0)" ::: "memory");
        __builtin_amdgcn_s_barrier();
    }
#undef G1_LOAD
#undef G1_WRITE

    // epilogue: bias + exact gelu, packed 8B stores
    const size_t hbase = ((size_t)(b * E_ + e) * C_ + m0) * H_;
    #pragma unroll
    for (int m = 0; m < 4; ++m) {
        const int cl = wm * 64 + m * 16 + l15;
        u16* rowp = Hbuf + hbase + (size_t)cl * H_;
        #pragma unroll
        for (int n = 0; n < 4; ++n) {
            const int hb = wn * 64 + n * 16 + lk * 4;
            u16 o[4];
            #pragma unroll
            for (int r = 0; r < 4; ++r) {
                float h = acc[m][n][r] + bs1[hb + r];
                float g = 0.5f * h * (1.0f + erff(h * 0.70710678118f));
                o[r] = f2bf(g);
            }
            *reinterpret_cast<u64*>(rowp + hb) = *reinterpret_cast<const u64*>(o);
        }
    }
}

// ---------------- GEMM2: Ybuf = ((Hbuf @ W2^T) + b2) * gate ----------------
// tile: 128 c-rows x 256 d-cols, K=256, 512 threads (8 waves 2Mx4N)
__global__ __launch_bounds__(512) void gemm2_v2(
    const u16* __restrict__ Hbuf, const u16* __restrict__ W2bf,
    const float* __restrict__ b2, const float* __restrict__ gate,
    u16* __restrict__ Ybuf)
{
    const int mt = blockIdx.x >> 3, nt = blockIdx.x & 7;
    const int be = blockIdx.y;
    const int b = be >> 3, e = be & 7;
    const int m0 = mt * 128, n0 = nt * 256;

    __shared__ __align__(16) u16 As[128 * 64];
    __shared__ __align__(16) u16 Bs[256 * 64];
    __shared__ float gs[128];
    __shared__ float bs2[256];

    const int tid = threadIdx.x;
    if (tid < 128) gs[tid] = gate[(b * E_ + e) * C_ + m0 + tid];
    if (tid < 256) bs2[tid] = b2[n0 + tid];
    __syncthreads();

    const int lane = tid & 63, wid = tid >> 6;
    const int wm = wid >> 2, wn = wid & 3;
    const int l15 = lane & 15, lk = lane >> 4;

    const int ar = tid >> 2, ac0 = tid & 3;
    const u16* aRow = Hbuf + ((size_t)(b * E_ + e) * C_ + m0 + ar) * H_;
    const int br = tid >> 1, bc0 = (tid & 1) * 4;
    const u16* bRow = W2bf + ((size_t)e * D_ + n0 + br) * H_;

    const int aOff0 = swz(ar, ac0), aOff1 = swz(ar, ac0 + 4);
    int bOff[4];
    #pragma unroll
    for (int j = 0; j < 4; ++j) bOff[j] = swz(br, bc0 + j);

    f32x4 acc[4][4];
    #pragma unroll
    for (int i = 0; i < 4; ++i)
        #pragma unroll
        for (int j = 0; j < 4; ++j)
            acc[i][j] = (f32x4){0.f, 0.f, 0.f, 0.f};

    short8 pa0, pa1, pb[4];
    pa0 = *reinterpret_cast<const short8*>(aRow + ac0 * 8);
    pa1 = *reinterpret_cast<const short8*>(aRow + (ac0 + 4) * 8);
    #pragma unroll
    for (int j = 0; j < 4; ++j)
        pb[j] = *reinterpret_cast<const short8*>(bRow + (bc0 + j) * 8);
    *reinterpret_cast<short8*>(&As[aOff0]) = pa0;
    *reinterpret_cast<short8*>(&As[aOff1]) = pa1;
    #pragma unroll
    for (int j = 0; j < 4; ++j)
        *reinterpret_cast<short8*>(&Bs[bOff[j]]) = pb[j];
    __syncthreads();

    const int NT = H_ / 64;  // 4
    for (int t = 0; t < NT; ++t) {
        if (t + 1 < NT) {
            const int k = (t + 1) * 64;
            pa0 = *reinterpret_cast<const short8*>(aRow + k + ac0 * 8);
            pa1 = *reinterpret_cast<const short8*>(aRow + k + (ac0 + 4) * 8);
            #pragma unroll
            for (int j = 0; j < 4; ++j)
                pb[j] = *reinterpret_cast<const short8*>(bRow + k + (bc0 + j) * 8);
        }
        #pragma unroll
        for (int kk = 0; kk < 2; ++kk) {
            short8 af[4], bfr[4];
            #pragma unroll
            for (int m = 0; m < 4; ++m) {
                const int row = wm * 64 + m * 16 + l15;
                af[m] = *reinterpret_cast<const short8*>(&As[swz(row, kk * 4 + lk)]);
            }
            #pragma unroll
            for (int n = 0; n < 4; ++n) {
                const int row = wn * 64 + n * 16 + l15;
                bfr[n] = *reinterpret_cast<const short8*>(&Bs[swz(row, kk * 4 + lk)]);
            }
            #pragma unroll
            for (int m = 0; m < 4; ++m)
                #pragma unroll
                for (int n = 0; n < 4; ++n)
                    acc[m][n] = __builtin_amdgcn_mfma_f32_16x16x32_bf16(
                        bfr[n], af[m], acc[m][n], 0, 0, 0);
        }
        if (t + 1 < NT) {
            __syncthreads();
            *reinterpret_cast<short8*>(&As[aOff0]) = pa0;
            *reinterpret_cast<short8*>(&As[aOff1]) = pa1;
            #pragma unroll
            for (int j = 0; j < 4; ++j)
                *reinterpret_cast<short8*>(&Bs[bOff[j]]) = pb[j];
            __syncthreads();
        }
    }

    // epilogue: (acc + b2) * gate -> bf16, packed 8B stores
    const size_t ybase = (size_t)(b * E_ + e) * C_ + m0;
    #pragma unroll
    for (int m = 0; m < 4; ++m) {
        const int cl = wm * 64 + m * 16 + l15;
        const float g = gs[cl];
        u16* rowp = Ybuf + (ybase + cl) * (size_t)D_ + n0;
        #pragma unroll
        for (int n = 0; n < 4; ++n) {
            const int db = wn * 64 + n * 16 + lk * 4;
            u16 o[4];
            #pragma unroll
            for (int r = 0; r < 4; ++r)
                o[r] = f2bf((acc[m][n][r] + bs2[db + r]) * g);
            *reinterpret_cast<u64*>(rowp + db) = *reinterpret_cast<const u64*>(o);
        }
    }
}

// ---------------- inverted index build ----------------
__global__ __launch_bounds__(256) void fill_kernel(
    const int* __restrict__ idx, int* __restrict__ cnt,
    int* __restrict__ slots)
{
    int i = blockIdx.x * 256 + threadIdx.x;
    if (i >= B_ * E_ * C_) return;
    int b = i / (E_ * C_);
    int slot = i % (E_ * C_);
    int t = idx[i];
    int p = atomicAdd(&cnt[b * T_ + t], 1);
    if (p < SLOTCAP) slots[(b * T_ + t) * SLOTCAP + p] = slot;
}

// ---------------- combine: out[b,t,:] = sum over slots of Ybuf ----------------
__global__ __launch_bounds__(256) void combine_kernel(
    const u16* __restrict__ Ybuf, const int* __restrict__ cnt,
    const int* __restrict__ slots, float* __restrict__ out)
{
    const int bt = blockIdx.x;               // b*T_ + t
    const int tid = threadIdx.x;
    __shared__ int sl[SLOTCAP];
    int n = cnt[bt];
    n = n > SLOTCAP ? SLOTCAP : n;
    if (tid < n) sl[tid] = slots[bt * SLOTCAP + tid];
    __syncthreads();
    const int b = bt >> 12;                  // T_ = 4096
    float a[8] = {0.f, 0.f, 0.f, 0.f, 0.f, 0.f, 0.f, 0.f};
    for (int s = 0; s < n; ++s) {
        const u16* yrow = Ybuf + ((size_t)b * (E_ * C_) + sl[s]) * D_ + tid * 8;
        short8 v = *reinterpret_cast<const short8*>(yrow);
        #pragma unroll
        for (int j = 0; j < 8; ++j) a[j] += bf2f((u16)v[j]);
    }
    float* orow = out + (size_t)bt * D_ + tid * 8;
    *reinterpret_cast<f32x4*>(orow)     = (f32x4){a[0], a[1], a[2], a[3]};
    *reinterpret_cast<f32x4*>(orow + 4) = (f32x4){a[4], a[5], a[6], a[7]};
}

extern "C" void kernel_launch(void* const* d_in, const int* in_sizes, int n_in,
                              void* d_out, int out_size, void* d_ws, size_t ws_size,
                              hipStream_t stream) {
    const float* x    = (const float*)d_in[0];
    const float* W1   = (const float*)d_in[1];
    const float* b1   = (const float*)d_in[2];
    const float* W2   = (const float*)d_in[3];
    const float* b2   = (const float*)d_in[4];
    const int*   idx  = (const int*)d_in[5];
    const float* gate = (const float*)d_in[6];
    float* out = (float*)d_out;

    const size_t nW = (size_t)E_ * H_ * D_;        // 4,194,304
    const size_t nH = (size_t)B_ * E_ * C_ * H_;   // 8,388,608
    const size_t nY = (size_t)B_ * E_ * C_ * D_;   // 67,108,864

    u16* W1bf = (u16*)d_ws;
    u16* W2bf = W1bf + nW;
    u16* Hbuf = W2bf + nW;
    u16* Ybuf = Hbuf + nH;
    int* cnt   = (int*)(Ybuf + nY);
    int* slots = cnt + (size_t)B_ * T_;

    hipMemsetAsync(cnt, 0, (size_t)B_ * T_ * sizeof(int), stream);
    conv_f32_bf16<<<(int)(nW / 1024), 256, 0, stream>>>(W1, W1bf, (int)nW);
    conv_f32_bf16<<<(int)(nW / 1024), 256, 0, stream>>>(W2, W2bf, (int)nW);
    fill_kernel<<<(B_ * E_ * C_) / 256, 256, 0, stream>>>(idx, cnt, slots);

    gemm1_v3<<<dim3(8, 32), 512, 0, stream>>>(x, W1bf, b1, idx, Hbuf);
    gemm2_v2<<<dim3(64, 32), 512, 0, stream>>>(Hbuf, W2bf, b2, gate, Ybuf);
    combine_kernel<<<B_ * T_, 256, 0, stream>>>(Ybuf, cnt, slots, out);
}